// Round 3
// baseline (474.478 us; speedup 1.0000x reference)
//
#include <hip/hip_runtime.h>

#define H 1024
#define W 1024

// Bit-exact emulation of the numpy/XLA fp32 reference:
//  - direct 9-tap correlation, row-major tap order, sequential fp32 adds
//    (products with ±1/±2/±4 are exact, so FMA contraction of the sums is
//    bit-harmless; only ADD order matters)
//  - det = p1 - p2 must NOT be fma-contracted (p1, p2 are inexact) ->
//    contract(off) for the whole function.
__device__ __forceinline__ float score_ref(
    float a00, float a01, float a02,
    float a10, float a11, float a12,
    float a20, float a21, float a22)
{
#pragma clang fp contract(off)
    // KXX = [[1,-2,1],[2,-4,2],[1,-2,1]]
    float gxx = a00;
    gxx = gxx - 2.0f * a01;
    gxx = gxx + a02;
    gxx = gxx + 2.0f * a10;
    gxx = gxx - 4.0f * a11;
    gxx = gxx + 2.0f * a12;
    gxx = gxx + a20;
    gxx = gxx - 2.0f * a21;
    gxx = gxx + a22;
    // KXY = [[-1,0,1],[0,0,0],[1,0,-1]]  (zero taps are bitwise no-ops)
    float gxy = -a00;
    gxy = gxy + a02;
    gxy = gxy + a20;
    gxy = gxy - a22;
    // KYY = KXX^T = [[1,2,1],[-2,-4,-2],[1,2,1]]
    float gyy = a00;
    gyy = gyy + 2.0f * a01;
    gyy = gyy + a02;
    gyy = gyy - 2.0f * a10;
    gyy = gyy - 4.0f * a11;
    gyy = gyy - 2.0f * a12;
    gyy = gyy + a20;
    gyy = gyy + 2.0f * a21;
    gyy = gyy + a22;

    float p1 = gxx * gyy;
    float p2 = gxy * gxy;
    float det = p1 - p2;
    float s = fabsf(det);
    return s > 1e-6f ? s : 1e-6f;
}

// ---------------- Kernel 1: per-plane max of scores -------------------------
__global__ __launch_bounds__(256) void hess_max_kernel(
    const float* __restrict__ x, unsigned int* __restrict__ pmax)
{
    const int plane = blockIdx.y;
    const int y0 = blockIdx.x * 32;
    const int t = threadIdx.x;
    const int c = t * 4;
    const float* px = x + (size_t)plane * H * W;

    float l0, l1, l2, r0, r1, r2;
    float4 m0, m1, m2;

    {   // row y0-1 (clamped)
        int rr = y0 - 1 < 0 ? 0 : y0 - 1;
        const float* p = px + (size_t)rr * W;
        m0 = *(const float4*)(p + c);
        l0 = p[c == 0 ? 0 : c - 1];
        r0 = p[c + 4 >= W ? W - 1 : c + 4];
    }
    {   // row y0
        const float* p = px + (size_t)y0 * W;
        m1 = *(const float4*)(p + c);
        l1 = p[c == 0 ? 0 : c - 1];
        r1 = p[c + 4 >= W ? W - 1 : c + 4];
    }

    float smax = 0.f;
    for (int y = y0; y < y0 + 32; ++y) {
        int rr = y + 1 >= H ? H - 1 : y + 1;
        const float* p = px + (size_t)rr * W;
        m2 = *(const float4*)(p + c);
        l2 = p[c == 0 ? 0 : c - 1];
        r2 = p[c + 4 >= W ? W - 1 : c + 4];

        float w0[6] = { l0, m0.x, m0.y, m0.z, m0.w, r0 };
        float w1[6] = { l1, m1.x, m1.y, m1.z, m1.w, r1 };
        float w2[6] = { l2, m2.x, m2.y, m2.z, m2.w, r2 };
#pragma unroll
        for (int j = 0; j < 4; ++j) {
            float s = score_ref(w0[j], w0[j+1], w0[j+2],
                                w1[j], w1[j+1], w1[j+2],
                                w2[j], w2[j+1], w2[j+2]);
            smax = fmaxf(smax, s);
        }
        m0 = m1; l0 = l1; r0 = r1;
        m1 = m2; l1 = l2; r1 = r2;
    }

    // wave reduce (64 lanes), one atomic per wave; scores > 0 so uint-bit
    // ordering == float ordering.
#pragma unroll
    for (int off = 32; off > 0; off >>= 1)
        smax = fmaxf(smax, __shfl_down(smax, off));
    if ((t & 63) == 0)
        atomicMax(pmax + plane, __float_as_uint(smax));
}

// ---------------- Kernel 2: scores + NMS + normalize -------------------------
#define TW 64
#define TH 16
#define IW 68   // TW + 4 halo
#define IH 20   // TH + 4
#define SW 66   // TW + 2
#define SH 18   // TH + 2
__global__ __launch_bounds__(256) void hess_out_kernel(
    const float* __restrict__ x, const unsigned int* __restrict__ pmax,
    float* __restrict__ out)
{
    __shared__ float lin[IH * IW];
    __shared__ float ls[SH * SW];
    const int plane = blockIdx.z;
    const int x0 = blockIdx.x * TW;
    const int y0 = blockIdx.y * TH;
    const int t = threadIdx.x;
    const float* px = x + (size_t)plane * H * W;

    // stage input tile + 2-halo with edge clamp (replicate padding)
    for (int i = t; i < IH * IW; i += 256) {
        int r = i / IW, cc = i % IW;
        int gy = y0 - 2 + r; gy = gy < 0 ? 0 : (gy >= H ? H - 1 : gy);
        int gx = x0 - 2 + cc; gx = gx < 0 ? 0 : (gx >= W ? W - 1 : gx);
        lin[i] = px[(size_t)gy * W + gx];
    }
    __syncthreads();

    // score tile + 1-halo; out-of-plane -> 0 (identity for max, scores>=1e-6)
    for (int i = t; i < SH * SW; i += 256) {
        int sy = i / SW, sx = i % SW;
        int gy = y0 - 1 + sy, gx = x0 - 1 + sx;
        float v = 0.f;
        if (gy >= 0 && gy < H && gx >= 0 && gx < W) {
            const float* p0 = &lin[sy * IW + sx];
            v = score_ref(p0[0], p0[1], p0[2],
                          p0[IW], p0[IW + 1], p0[IW + 2],
                          p0[2 * IW], p0[2 * IW + 1], p0[2 * IW + 2]);
        }
        ls[i] = v;
    }
    __syncthreads();

    const float smax = __uint_as_float(pmax[plane]);
    const int ox = t & 63;
    const int oyb = t >> 6;           // 0..3
#pragma unroll
    for (int k = 0; k < 4; ++k) {
        int oy = oyb * 4 + k;         // 0..15
        const float* p = &ls[oy * SW + ox];
        float s = p[SW + 1];
        float m = fmaxf(fmaxf(fmaxf(p[0], p[1]), fmaxf(p[2], p[SW])),
                        fmaxf(fmaxf(p[SW + 1], p[SW + 2]),
                              fmaxf(fmaxf(p[2 * SW], p[2 * SW + 1]), p[2 * SW + 2])));
        float v = (s == m) ? s / smax : 0.f;
        out[(size_t)plane * H * W + (size_t)(y0 + oy) * W + (x0 + ox)] = v;
    }
}

extern "C" void kernel_launch(void* const* d_in, const int* in_sizes, int n_in,
                              void* d_out, int out_size, void* d_ws, size_t ws_size,
                              hipStream_t stream) {
    const float* x = (const float*)d_in[0];
    float* out = (float*)d_out;
    unsigned int* pmax = (unsigned int*)d_ws;
    const int planes = in_sizes[0] / (H * W);   // 48

    hipMemsetAsync(pmax, 0, planes * sizeof(unsigned int), stream);

    dim3 g1(H / 32, planes);
    hess_max_kernel<<<g1, 256, 0, stream>>>(x, pmax);

    dim3 g2(W / TW, H / TH, planes);
    hess_out_kernel<<<g2, 256, 0, stream>>>(x, pmax, out);
}